// Round 14
// baseline (424.251 us; speedup 1.0000x reference)
//
#include <hip/hip_runtime.h>

#define NNODES 100000
#define FDIM 128
#define NLAYERS 5

typedef __bf16 bf16_t;
typedef bf16_t bf16x8 __attribute__((ext_vector_type(8)));
typedef float  f32x4  __attribute__((ext_vector_type(4)));

__device__ __forceinline__ bf16_t f2bf(float f){ return (bf16_t)f; }
__device__ __forceinline__ float bfbits_lo(unsigned u){
  unsigned b = u << 16; return __builtin_bit_cast(float, b);
}
__device__ __forceinline__ float bfbits_hi(unsigned u){
  unsigned b = u & 0xffff0000u; return __builtin_bit_cast(float, b);
}
__device__ __forceinline__ unsigned short bfb(float f){
  bf16_t b = (bf16_t)f; return __builtin_bit_cast(unsigned short, b);
}
__device__ __forceinline__ float us2f(unsigned short u){
  unsigned b = ((unsigned)u) << 16; return __builtin_bit_cast(float, b);
}

// ---------------- CSR build ----------------
__global__ void deg_kernel(const int* __restrict__ dstv, int* __restrict__ deg, int E){
  int e = blockIdx.x*256 + threadIdx.x;
  if(e < E) atomicAdd(&deg[dstv[e]], 1);
}

__global__ void scan1_kernel(const int* __restrict__ deg, int* __restrict__ row_start,
                             int* __restrict__ sums, int n){
  __shared__ int sm[256];
  int t = threadIdx.x;
  int base = blockIdx.x*1024 + t*4;
  int v0=0,v1=0,v2=0,v3=0;
  if(base+3 < n){ int4 q = *(const int4*)(deg+base); v0=q.x; v1=q.y; v2=q.z; v3=q.w; }
  else {
    if(base   < n) v0 = deg[base];
    if(base+1 < n) v1 = deg[base+1];
    if(base+2 < n) v2 = deg[base+2];
    if(base+3 < n) v3 = deg[base+3];
  }
  int s = v0+v1+v2+v3;
  sm[t] = s;
  __syncthreads();
  for(int off=1; off<256; off<<=1){
    int y = (t>=off) ? sm[t-off] : 0;
    __syncthreads();
    sm[t] += y;
    __syncthreads();
  }
  int excl = sm[t] - s;
  if(base   < n) row_start[base]   = excl;
  if(base+1 < n) row_start[base+1] = excl+v0;
  if(base+2 < n) row_start[base+2] = excl+v0+v1;
  if(base+3 < n) row_start[base+3] = excl+v0+v1+v2;
  if(t == 255) sums[blockIdx.x] = sm[255];
}

__global__ void scan2_kernel(int* sums, int nc){
  __shared__ int sm[128];
  int t = threadIdx.x;
  int v = (t<nc) ? sums[t] : 0;
  sm[t] = v;
  __syncthreads();
  for(int off=1; off<128; off<<=1){
    int y = (t>=off) ? sm[t-off] : 0;
    __syncthreads();
    sm[t] += y;
    __syncthreads();
  }
  if(t<nc) sums[t] = sm[t] - v;
}

__global__ void scan3_kernel(int* row_start, const int* __restrict__ sums, int n, int E){
  int i = blockIdx.x*256 + threadIdx.x;
  if(i < n)       row_start[i] += sums[i>>10];
  else if(i == n) row_start[n]  = E;
}

__global__ void fill_kernel(const int* __restrict__ srcv, const int* __restrict__ dstv,
                            const int* __restrict__ row_start, int* __restrict__ cnt,
                            int* __restrict__ csr, int E){
  int e = blockIdx.x*256 + threadIdx.x;
  if(e < E){
    int d = dstv[e];
    int p = atomicAdd(&cnt[d], 1);
    csr[row_start[d] + p] = srcv[e];
  }
}

// ---------------- merged prep: cvt (x->bf16) | wprep | zero ----------------
// grid = [0,6250): cvt   [6250,6330): wprep   [6330,6526): zero degcnt
__global__ __launch_bounds__(256) void prep_kernel(
    const float* __restrict__ x, unsigned short* __restrict__ xb,
    const float* __restrict__ Wrel, const float* __restrict__ Wroot,
    bf16_t* __restrict__ Bp, int4* __restrict__ zp, int zn4){
  int bid = blockIdx.x;
  if(bid < 6250){
    long i = ((long)bid*256 + threadIdx.x)*8;
    float4 q0 = *(const float4*)(x+i);
    float4 q1 = *(const float4*)(x+i+4);
    unsigned short o[8];
    o[0]=bfb(q0.x); o[1]=bfb(q0.y); o[2]=bfb(q0.z); o[3]=bfb(q0.w);
    o[4]=bfb(q1.x); o[5]=bfb(q1.y); o[6]=bfb(q1.z); o[7]=bfb(q1.w);
    *(ulong2*)(xb+i) = *(ulong2*)o;
  } else if(bid < 6330){
    int gid = (bid-6250)*256 + threadIdx.x;
    if(gid >= NLAYERS*64*64) return;
    int lane = gid & 63;
    int fg   = (gid>>6) & 63;
    int l    = gid >> 12;
    int kk = fg >> 3, cb = fg & 7;
    int kbase = kk*32 + (lane>>4)*8;
    int col   = cb*16 + (lane&15);
    bf16_t tmp[8];
    #pragma unroll
    for(int e=0;e<8;e++){
      int k = kbase + e;
      float v = (k < FDIM) ? Wrel [l*FDIM*FDIM + k*FDIM + col]
                           : Wroot[l*FDIM*FDIM + (k-FDIM)*FDIM + col];
      tmp[e] = f2bf(v);
    }
    bf16_t* o = Bp + (long)gid*8;
    #pragma unroll
    for(int e=0;e<8;e++) o[e] = tmp[e];
  } else {
    int i = (bid-6330)*256 + threadIdx.x;
    if(i < zn4) zp[i] = make_int4(0,0,0,0);
  }
}

// ---------------- gather v4: wave-per-node, predicated single-exposure tail ----
// Same shape as R8 (proven best) but the 4/2/1 tail ladder is replaced by ONE
// predicated 8-burst: all remaining loads issue back-to-back (conditions are
// wave-uniform scalar branches, no data dependency between loads), so a
// deg<=8 node (~80% at mean deg 6) pays ONE L3 latency exposure, not two.
__global__ __launch_bounds__(256) void gather_kernel(const unsigned short* __restrict__ xb,
                                                     const int* __restrict__ row_start,
                                                     const int* __restrict__ csr,
                                                     unsigned short* __restrict__ agg, int n){
  int wid  = (blockIdx.x*256 + threadIdx.x) >> 6;
  int lane = threadIdx.x & 63;
  if(wid >= n) return;
  int s0 = row_start[wid];
  int s1 = row_start[wid+1];
  float ax[8] = {}, ay[8] = {};
  int i = s0;
  for(; i+8 <= s1; i += 8){
    unsigned v[8];
    #pragma unroll
    for(int j=0;j<8;j++){
      int c = csr[i+j];
      v[j] = *(const unsigned*)(xb + (size_t)c*FDIM + lane*2);
    }
    #pragma unroll
    for(int j=0;j<8;j++){ ax[j] += bfbits_lo(v[j]); ay[j] += bfbits_hi(v[j]); }
  }
  int rem = s1 - i;                       // 0..7, wave-uniform
  {
    unsigned v[8];
    #pragma unroll
    for(int j=0;j<8;j++){
      if(j < rem){
        int c = csr[i+j];
        v[j] = *(const unsigned*)(xb + (size_t)c*FDIM + lane*2);
      }
    }
    #pragma unroll
    for(int j=0;j<8;j++){
      if(j < rem){ ax[j] += bfbits_lo(v[j]); ay[j] += bfbits_hi(v[j]); }
    }
  }
  float axs = ((ax[0]+ax[1])+(ax[2]+ax[3])) + ((ax[4]+ax[5])+(ax[6]+ax[7]));
  float ays = ((ay[0]+ay[1])+(ay[2]+ay[3])) + ((ay[4]+ay[5])+(ay[6]+ay[7]));
  unsigned o = (unsigned)bfb(axs) | ((unsigned)bfb(ays) << 16);
  *(unsigned*)(agg + (size_t)wid*FDIM + lane*2) = o;
}

// ---------------- GEMM v2 (R11, proven): block-tile, A in LDS, 2 cb/wave ----
__global__ __launch_bounds__(256) void gemm_kernel(
    const bf16_t* __restrict__ Aagg, const bf16_t* __restrict__ Ain,
    const bf16_t* __restrict__ Bp, const float* __restrict__ bias,
    bf16_t* __restrict__ outB, float* __restrict__ outF,
    int relu, int resf){
  __shared__ char As[8192];          // [0,4096): agg tile, [4096,8192): xin tile
  int tid  = threadIdx.x;
  int lane = tid & 63;
  int wv   = tid >> 6;               // 0..3
  long tile0 = (long)blockIdx.x*16;

  // stage: thread t -> row t>>4, 16B chunk t&15 (coalesced global reads)
  {
    int row = tid >> 4, c16 = tid & 15;
    int so  = c16*16;
    int sw  = so ^ ((row & 7) << 4);
    ulong2 va = *(const ulong2*)((const char*)Aagg + (tile0+row)*256 + so);
    ulong2 vi = *(const ulong2*)((const char*)Ain  + (tile0+row)*256 + so);
    *(ulong2*)(As + row*256 + sw)        = va;
    *(ulong2*)(As + 4096 + row*256 + sw) = vi;
  }
  __syncthreads();

  // MFMA: this wave owns cb blocks {2wv, 2wv+1}
  int r_lo = lane & 15;
  int kgrp = lane >> 4;
  int cb0 = wv*2, cb1 = wv*2+1;
  f32x4 acc0 = {}, acc1 = {};
  #pragma unroll
  for(int kk=0;kk<8;kk++){
    const char* base = (kk<4) ? As : (As + 4096);
    int X = (kk&3)*64 + kgrp*16;
    bf16x8 a = *(const bf16x8*)(base + r_lo*256 + (X ^ ((r_lo&7)<<4)));
    bf16x8 w0 = *(const bf16x8*)(Bp + (((kk<<3)|cb0)*64 + lane)*8);
    bf16x8 w1 = *(const bf16x8*)(Bp + (((kk<<3)|cb1)*64 + lane)*8);
    acc0 = __builtin_amdgcn_mfma_f32_16x16x32_bf16(w0, a, acc0, 0, 0, 0);
    acc1 = __builtin_amdgcn_mfma_f32_16x16x32_bf16(w1, a, acc1, 0, 0, 0);
  }

  // epilogue: lane owns row tile0+r_lo, cols cb*16 + kgrp*4 .. +3
  long nrow = tile0 + r_lo;
  #pragma unroll
  for(int h=0; h<2; h++){
    int cb = h ? cb1 : cb0;
    f32x4 acc = h ? acc1 : acc0;
    int col = cb*16 + kgrp*4;
    float4 bv = *(const float4*)(bias + col);
    float v0 = acc[0] + bv.x;
    float v1 = acc[1] + bv.y;
    float v2 = acc[2] + bv.z;
    float v3 = acc[3] + bv.w;
    if(relu){ v0=fmaxf(v0,0.f); v1=fmaxf(v1,0.f); v2=fmaxf(v2,0.f); v3=fmaxf(v3,0.f); }
    if(resf){
      ushort4 rv = *(const ushort4*)(As + 4096 + r_lo*256 + ((col*2) ^ ((r_lo&7)<<4)));
      v0 += us2f(rv.x); v1 += us2f(rv.y); v2 += us2f(rv.z); v3 += us2f(rv.w);
    }
    if(outF){
      float4 o; o.x=v0; o.y=v1; o.z=v2; o.w=v3;
      *(float4*)(outF + nrow*FDIM + col) = o;
    } else {
      uint2 o;
      o.x = (unsigned)bfb(v0) | ((unsigned)bfb(v1) << 16);
      o.y = (unsigned)bfb(v2) | ((unsigned)bfb(v3) << 16);
      *(uint2*)((unsigned short*)outB + nrow*FDIM + col) = o;
    }
  }
}

extern "C" void kernel_launch(void* const* d_in, const int* in_sizes, int n_in,
                              void* d_out, int out_size, void* d_ws, size_t ws_size,
                              hipStream_t stream){
  const float* x     = (const float*)d_in[0];
  const int*   ei    = (const int*)  d_in[1];
  const float* Wrel  = (const float*)d_in[2];
  const float* brel  = (const float*)d_in[3];
  const float* Wroot = (const float*)d_in[4];
  float* out = (float*)d_out;

  const int N = NNODES;
  const int E = in_sizes[1] / 2;
  const int* srcv = ei;
  const int* dstv = ei + E;

  char* w = (char*)d_ws;
  auto alloc = [&](size_t b)->char*{ char* p = w; w += (b + 255) & ~(size_t)255; return p; };
  unsigned short* xb  = (unsigned short*)alloc((size_t)N*FDIM*2);
  unsigned short* h_a = (unsigned short*)alloc((size_t)N*FDIM*2);
  unsigned short* h_b = (unsigned short*)alloc((size_t)N*FDIM*2);
  unsigned short* agg = (unsigned short*)alloc((size_t)N*FDIM*2);
  int*    degcnt    = (int*)   alloc((size_t)2*N*4);   // [0,N): deg, [N,2N): cnt
  int*    row_start = (int*)   alloc((size_t)(N+1)*4);
  int*    csr       = (int*)   alloc((size_t)E*4);
  bf16_t* Bp        = (bf16_t*)alloc((size_t)NLAYERS*4096*8*2);
  int*    sums      = (int*)   alloc(512);
  int* deg = degcnt;
  int* cnt = degcnt + N;

  int eb = (E + 255) / 256;
  int nchunks = (N + 1023) / 1024;
  prep_kernel <<<6526, 256, 0, stream>>>(x, xb, Wrel, Wroot, Bp,
                                         (int4*)degcnt, 2*N/4);
  deg_kernel <<<eb, 256, 0, stream>>>(dstv, deg, E);
  scan1_kernel<<<nchunks, 256, 0, stream>>>(deg, row_start, sums, N);
  scan2_kernel<<<1, 128, 0, stream>>>(sums, nchunks);
  scan3_kernel<<<(N + 1 + 255)/256, 256, 0, stream>>>(row_start, sums, N, E);
  fill_kernel<<<eb, 256, 0, stream>>>(srcv, dstv, row_start, cnt, csr, E);

  const int gtiles  = N / 16;                 // 6250 blocks for gemm

  typedef unsigned short us;
  struct Lay { const us* in; us* o; int relu; int res; };
  Lay L[5] = {
    { xb,  h_a, 1, 0 },
    { h_a, h_b, 1, 1 },
    { h_b, h_a, 1, 1 },
    { h_a, h_b, 1, 1 },
    { h_b, 0,   0, 1 },
  };
  for(int l=0; l<NLAYERS; l++){
    gather_kernel<<<N/4, 256, 0, stream>>>(L[l].in, row_start, csr, agg, N);
    gemm_kernel  <<<gtiles, 256, 0, stream>>>((const bf16_t*)agg, (const bf16_t*)L[l].in,
                                              Bp + (size_t)l*4096*8,
                                              brel + l*FDIM,
                                              (bf16_t*)L[l].o, (l==4)? out : nullptr,
                                              L[l].relu, L[l].res);
  }
}

// Round 15
// 423.342 us; speedup vs baseline: 1.0021x; 1.0021x over previous
//
#include <hip/hip_runtime.h>

#define NNODES 100000
#define FDIM 128
#define NLAYERS 5

typedef __bf16 bf16_t;
typedef bf16_t bf16x8 __attribute__((ext_vector_type(8)));
typedef float  f32x4  __attribute__((ext_vector_type(4)));

__device__ __forceinline__ bf16_t f2bf(float f){ return (bf16_t)f; }
__device__ __forceinline__ float bfbits_lo(unsigned u){
  unsigned b = u << 16; return __builtin_bit_cast(float, b);
}
__device__ __forceinline__ float bfbits_hi(unsigned u){
  unsigned b = u & 0xffff0000u; return __builtin_bit_cast(float, b);
}
__device__ __forceinline__ unsigned short bfb(float f){
  bf16_t b = (bf16_t)f; return __builtin_bit_cast(unsigned short, b);
}
__device__ __forceinline__ float us2f(unsigned short u){
  unsigned b = ((unsigned)u) << 16; return __builtin_bit_cast(float, b);
}

// ---------------- CSR build ----------------
__global__ void deg_kernel(const int* __restrict__ dstv, int* __restrict__ deg, int E){
  int e = blockIdx.x*256 + threadIdx.x;
  if(e < E) atomicAdd(&deg[dstv[e]], 1);
}

__global__ void scan1_kernel(const int* __restrict__ deg, int* __restrict__ row_start,
                             int* __restrict__ sums, int n){
  __shared__ int sm[256];
  int t = threadIdx.x;
  int base = blockIdx.x*1024 + t*4;
  int v0=0,v1=0,v2=0,v3=0;
  if(base+3 < n){ int4 q = *(const int4*)(deg+base); v0=q.x; v1=q.y; v2=q.z; v3=q.w; }
  else {
    if(base   < n) v0 = deg[base];
    if(base+1 < n) v1 = deg[base+1];
    if(base+2 < n) v2 = deg[base+2];
    if(base+3 < n) v3 = deg[base+3];
  }
  int s = v0+v1+v2+v3;
  sm[t] = s;
  __syncthreads();
  for(int off=1; off<256; off<<=1){
    int y = (t>=off) ? sm[t-off] : 0;
    __syncthreads();
    sm[t] += y;
    __syncthreads();
  }
  int excl = sm[t] - s;
  if(base   < n) row_start[base]   = excl;
  if(base+1 < n) row_start[base+1] = excl+v0;
  if(base+2 < n) row_start[base+2] = excl+v0+v1;
  if(base+3 < n) row_start[base+3] = excl+v0+v1+v2;
  if(t == 255) sums[blockIdx.x] = sm[255];
}

__global__ void scan2_kernel(int* sums, int nc){
  __shared__ int sm[128];
  int t = threadIdx.x;
  int v = (t<nc) ? sums[t] : 0;
  sm[t] = v;
  __syncthreads();
  for(int off=1; off<128; off<<=1){
    int y = (t>=off) ? sm[t-off] : 0;
    __syncthreads();
    sm[t] += y;
    __syncthreads();
  }
  if(t<nc) sums[t] = sm[t] - v;
}

__global__ void scan3_kernel(int* row_start, const int* __restrict__ sums, int n, int E){
  int i = blockIdx.x*256 + threadIdx.x;
  if(i < n)       row_start[i] += sums[i>>10];
  else if(i == n) row_start[n]  = E;
}

__global__ void fill_kernel(const int* __restrict__ srcv, const int* __restrict__ dstv,
                            const int* __restrict__ row_start, int* __restrict__ cnt,
                            int* __restrict__ csr, int E){
  int e = blockIdx.x*256 + threadIdx.x;
  if(e < E){
    int d = dstv[e];
    int p = atomicAdd(&cnt[d], 1);
    csr[row_start[d] + p] = srcv[e];
  }
}

// ---------------- merged prep: cvt (x->bf16) | wprep | zero ----------------
// grid = [0,6250): cvt   [6250,6330): wprep   [6330,6526): zero degcnt
__global__ __launch_bounds__(256) void prep_kernel(
    const float* __restrict__ x, unsigned short* __restrict__ xb,
    const float* __restrict__ Wrel, const float* __restrict__ Wroot,
    bf16_t* __restrict__ Bp, int4* __restrict__ zp, int zn4){
  int bid = blockIdx.x;
  if(bid < 6250){
    long i = ((long)bid*256 + threadIdx.x)*8;
    float4 q0 = *(const float4*)(x+i);
    float4 q1 = *(const float4*)(x+i+4);
    unsigned short o[8];
    o[0]=bfb(q0.x); o[1]=bfb(q0.y); o[2]=bfb(q0.z); o[3]=bfb(q0.w);
    o[4]=bfb(q1.x); o[5]=bfb(q1.y); o[6]=bfb(q1.z); o[7]=bfb(q1.w);
    *(ulong2*)(xb+i) = *(ulong2*)o;
  } else if(bid < 6330){
    int gid = (bid-6250)*256 + threadIdx.x;
    if(gid >= NLAYERS*64*64) return;
    int lane = gid & 63;
    int fg   = (gid>>6) & 63;
    int l    = gid >> 12;
    int kk = fg >> 3, cb = fg & 7;
    int kbase = kk*32 + (lane>>4)*8;
    int col   = cb*16 + (lane&15);
    bf16_t tmp[8];
    #pragma unroll
    for(int e=0;e<8;e++){
      int k = kbase + e;
      float v = (k < FDIM) ? Wrel [l*FDIM*FDIM + k*FDIM + col]
                           : Wroot[l*FDIM*FDIM + (k-FDIM)*FDIM + col];
      tmp[e] = f2bf(v);
    }
    bf16_t* o = Bp + (long)gid*8;
    #pragma unroll
    for(int e=0;e<8;e++) o[e] = tmp[e];
  } else {
    int i = (bid-6330)*256 + threadIdx.x;
    if(i < zn4) zp[i] = make_int4(0,0,0,0);
  }
}

// ---------------- gather v4: wave-per-node, predicated single-exposure tail ----
// Same shape as R8 (proven best) but the 4/2/1 tail ladder is replaced by ONE
// predicated 8-burst: all remaining loads issue back-to-back (conditions are
// wave-uniform scalar branches, no data dependency between loads), so a
// deg<=8 node (~80% at mean deg 6) pays ONE L3 latency exposure, not two.
__global__ __launch_bounds__(256) void gather_kernel(const unsigned short* __restrict__ xb,
                                                     const int* __restrict__ row_start,
                                                     const int* __restrict__ csr,
                                                     unsigned short* __restrict__ agg, int n){
  int wid  = (blockIdx.x*256 + threadIdx.x) >> 6;
  int lane = threadIdx.x & 63;
  if(wid >= n) return;
  int s0 = row_start[wid];
  int s1 = row_start[wid+1];
  float ax[8] = {}, ay[8] = {};
  int i = s0;
  for(; i+8 <= s1; i += 8){
    unsigned v[8];
    #pragma unroll
    for(int j=0;j<8;j++){
      int c = csr[i+j];
      v[j] = *(const unsigned*)(xb + (size_t)c*FDIM + lane*2);
    }
    #pragma unroll
    for(int j=0;j<8;j++){ ax[j] += bfbits_lo(v[j]); ay[j] += bfbits_hi(v[j]); }
  }
  int rem = s1 - i;                       // 0..7, wave-uniform
  {
    unsigned v[8];
    #pragma unroll
    for(int j=0;j<8;j++){
      if(j < rem){
        int c = csr[i+j];
        v[j] = *(const unsigned*)(xb + (size_t)c*FDIM + lane*2);
      }
    }
    #pragma unroll
    for(int j=0;j<8;j++){
      if(j < rem){ ax[j] += bfbits_lo(v[j]); ay[j] += bfbits_hi(v[j]); }
    }
  }
  float axs = ((ax[0]+ax[1])+(ax[2]+ax[3])) + ((ax[4]+ax[5])+(ax[6]+ax[7]));
  float ays = ((ay[0]+ay[1])+(ay[2]+ay[3])) + ((ay[4]+ay[5])+(ay[6]+ay[7]));
  unsigned o = (unsigned)bfb(axs) | ((unsigned)bfb(ays) << 16);
  *(unsigned*)(agg + (size_t)wid*FDIM + lane*2) = o;
}

// ---------------- GEMM v2 (R11, proven): block-tile, A in LDS, 2 cb/wave ----
__global__ __launch_bounds__(256) void gemm_kernel(
    const bf16_t* __restrict__ Aagg, const bf16_t* __restrict__ Ain,
    const bf16_t* __restrict__ Bp, const float* __restrict__ bias,
    bf16_t* __restrict__ outB, float* __restrict__ outF,
    int relu, int resf){
  __shared__ char As[8192];          // [0,4096): agg tile, [4096,8192): xin tile
  int tid  = threadIdx.x;
  int lane = tid & 63;
  int wv   = tid >> 6;               // 0..3
  long tile0 = (long)blockIdx.x*16;

  // stage: thread t -> row t>>4, 16B chunk t&15 (coalesced global reads)
  {
    int row = tid >> 4, c16 = tid & 15;
    int so  = c16*16;
    int sw  = so ^ ((row & 7) << 4);
    ulong2 va = *(const ulong2*)((const char*)Aagg + (tile0+row)*256 + so);
    ulong2 vi = *(const ulong2*)((const char*)Ain  + (tile0+row)*256 + so);
    *(ulong2*)(As + row*256 + sw)        = va;
    *(ulong2*)(As + 4096 + row*256 + sw) = vi;
  }
  __syncthreads();

  // MFMA: this wave owns cb blocks {2wv, 2wv+1}
  int r_lo = lane & 15;
  int kgrp = lane >> 4;
  int cb0 = wv*2, cb1 = wv*2+1;
  f32x4 acc0 = {}, acc1 = {};
  #pragma unroll
  for(int kk=0;kk<8;kk++){
    const char* base = (kk<4) ? As : (As + 4096);
    int X = (kk&3)*64 + kgrp*16;
    bf16x8 a = *(const bf16x8*)(base + r_lo*256 + (X ^ ((r_lo&7)<<4)));
    bf16x8 w0 = *(const bf16x8*)(Bp + (((kk<<3)|cb0)*64 + lane)*8);
    bf16x8 w1 = *(const bf16x8*)(Bp + (((kk<<3)|cb1)*64 + lane)*8);
    acc0 = __builtin_amdgcn_mfma_f32_16x16x32_bf16(w0, a, acc0, 0, 0, 0);
    acc1 = __builtin_amdgcn_mfma_f32_16x16x32_bf16(w1, a, acc1, 0, 0, 0);
  }

  // epilogue: lane owns row tile0+r_lo, cols cb*16 + kgrp*4 .. +3
  long nrow = tile0 + r_lo;
  #pragma unroll
  for(int h=0; h<2; h++){
    int cb = h ? cb1 : cb0;
    f32x4 acc = h ? acc1 : acc0;
    int col = cb*16 + kgrp*4;
    float4 bv = *(const float4*)(bias + col);
    float v0 = acc[0] + bv.x;
    float v1 = acc[1] + bv.y;
    float v2 = acc[2] + bv.z;
    float v3 = acc[3] + bv.w;
    if(relu){ v0=fmaxf(v0,0.f); v1=fmaxf(v1,0.f); v2=fmaxf(v2,0.f); v3=fmaxf(v3,0.f); }
    if(resf){
      ushort4 rv = *(const ushort4*)(As + 4096 + r_lo*256 + ((col*2) ^ ((r_lo&7)<<4)));
      v0 += us2f(rv.x); v1 += us2f(rv.y); v2 += us2f(rv.z); v3 += us2f(rv.w);
    }
    if(outF){
      float4 o; o.x=v0; o.y=v1; o.z=v2; o.w=v3;
      *(float4*)(outF + nrow*FDIM + col) = o;
    } else {
      uint2 o;
      o.x = (unsigned)bfb(v0) | ((unsigned)bfb(v1) << 16);
      o.y = (unsigned)bfb(v2) | ((unsigned)bfb(v3) << 16);
      *(uint2*)((unsigned short*)outB + nrow*FDIM + col) = o;
    }
  }
}

extern "C" void kernel_launch(void* const* d_in, const int* in_sizes, int n_in,
                              void* d_out, int out_size, void* d_ws, size_t ws_size,
                              hipStream_t stream){
  const float* x     = (const float*)d_in[0];
  const int*   ei    = (const int*)  d_in[1];
  const float* Wrel  = (const float*)d_in[2];
  const float* brel  = (const float*)d_in[3];
  const float* Wroot = (const float*)d_in[4];
  float* out = (float*)d_out;

  const int N = NNODES;
  const int E = in_sizes[1] / 2;
  const int* srcv = ei;
  const int* dstv = ei + E;

  char* w = (char*)d_ws;
  auto alloc = [&](size_t b)->char*{ char* p = w; w += (b + 255) & ~(size_t)255; return p; };
  unsigned short* xb  = (unsigned short*)alloc((size_t)N*FDIM*2);
  unsigned short* h_a = (unsigned short*)alloc((size_t)N*FDIM*2);
  unsigned short* h_b = (unsigned short*)alloc((size_t)N*FDIM*2);
  unsigned short* agg = (unsigned short*)alloc((size_t)N*FDIM*2);
  int*    degcnt    = (int*)   alloc((size_t)2*N*4);   // [0,N): deg, [N,2N): cnt
  int*    row_start = (int*)   alloc((size_t)(N+1)*4);
  int*    csr       = (int*)   alloc((size_t)E*4);
  bf16_t* Bp        = (bf16_t*)alloc((size_t)NLAYERS*4096*8*2);
  int*    sums      = (int*)   alloc(512);
  int* deg = degcnt;
  int* cnt = degcnt + N;

  int eb = (E + 255) / 256;
  int nchunks = (N + 1023) / 1024;
  prep_kernel <<<6526, 256, 0, stream>>>(x, xb, Wrel, Wroot, Bp,
                                         (int4*)degcnt, 2*N/4);
  deg_kernel <<<eb, 256, 0, stream>>>(dstv, deg, E);
  scan1_kernel<<<nchunks, 256, 0, stream>>>(deg, row_start, sums, N);
  scan2_kernel<<<1, 128, 0, stream>>>(sums, nchunks);
  scan3_kernel<<<(N + 1 + 255)/256, 256, 0, stream>>>(row_start, sums, N, E);
  fill_kernel<<<eb, 256, 0, stream>>>(srcv, dstv, row_start, cnt, csr, E);

  const int gtiles  = N / 16;                 // 6250 blocks for gemm

  typedef unsigned short us;
  struct Lay { const us* in; us* o; int relu; int res; };
  Lay L[5] = {
    { xb,  h_a, 1, 0 },
    { h_a, h_b, 1, 1 },
    { h_b, h_a, 1, 1 },
    { h_a, h_b, 1, 1 },
    { h_b, 0,   0, 1 },
  };
  for(int l=0; l<NLAYERS; l++){
    gather_kernel<<<N/4, 256, 0, stream>>>(L[l].in, row_start, csr, agg, N);
    gemm_kernel  <<<gtiles, 256, 0, stream>>>((const bf16_t*)agg, (const bf16_t*)L[l].in,
                                              Bp + (size_t)l*4096*8,
                                              brel + l*FDIM,
                                              (bf16_t*)L[l].o, (l==4)? out : nullptr,
                                              L[l].relu, L[l].res);
  }
}

// Round 16
// 385.927 us; speedup vs baseline: 1.0993x; 1.0969x over previous
//
#include <hip/hip_runtime.h>

#define NNODES 100000
#define FDIM 128
#define NLAYERS 5

typedef __bf16 bf16_t;
typedef bf16_t bf16x8 __attribute__((ext_vector_type(8)));
typedef float  f32x4  __attribute__((ext_vector_type(4)));

__device__ __forceinline__ bf16_t f2bf(float f){ return (bf16_t)f; }
__device__ __forceinline__ float bfbits_lo(unsigned u){
  unsigned b = u << 16; return __builtin_bit_cast(float, b);
}
__device__ __forceinline__ float bfbits_hi(unsigned u){
  unsigned b = u & 0xffff0000u; return __builtin_bit_cast(float, b);
}
__device__ __forceinline__ unsigned short bfb(float f){
  bf16_t b = (bf16_t)f; return __builtin_bit_cast(unsigned short, b);
}
__device__ __forceinline__ float us2f(unsigned short u){
  unsigned b = ((unsigned)u) << 16; return __builtin_bit_cast(float, b);
}

// ---------------- CSR build ----------------
__global__ void deg_kernel(const int* __restrict__ dstv, int* __restrict__ deg, int E){
  int e = blockIdx.x*256 + threadIdx.x;
  if(e < E) atomicAdd(&deg[dstv[e]], 1);
}

__global__ void scan1_kernel(const int* __restrict__ deg, int* __restrict__ row_start,
                             int* __restrict__ sums, int n){
  __shared__ int sm[256];
  int t = threadIdx.x;
  int base = blockIdx.x*1024 + t*4;
  int v0=0,v1=0,v2=0,v3=0;
  if(base+3 < n){ int4 q = *(const int4*)(deg+base); v0=q.x; v1=q.y; v2=q.z; v3=q.w; }
  else {
    if(base   < n) v0 = deg[base];
    if(base+1 < n) v1 = deg[base+1];
    if(base+2 < n) v2 = deg[base+2];
    if(base+3 < n) v3 = deg[base+3];
  }
  int s = v0+v1+v2+v3;
  sm[t] = s;
  __syncthreads();
  for(int off=1; off<256; off<<=1){
    int y = (t>=off) ? sm[t-off] : 0;
    __syncthreads();
    sm[t] += y;
    __syncthreads();
  }
  int excl = sm[t] - s;
  if(base   < n) row_start[base]   = excl;
  if(base+1 < n) row_start[base+1] = excl+v0;
  if(base+2 < n) row_start[base+2] = excl+v0+v1;
  if(base+3 < n) row_start[base+3] = excl+v0+v1+v2;
  if(t == 255) sums[blockIdx.x] = sm[255];
}

__global__ void scan2_kernel(int* sums, int nc){
  __shared__ int sm[128];
  int t = threadIdx.x;
  int v = (t<nc) ? sums[t] : 0;
  sm[t] = v;
  __syncthreads();
  for(int off=1; off<128; off<<=1){
    int y = (t>=off) ? sm[t-off] : 0;
    __syncthreads();
    sm[t] += y;
    __syncthreads();
  }
  if(t<nc) sums[t] = sm[t] - v;
}

__global__ void scan3_kernel(int* row_start, const int* __restrict__ sums, int n, int E){
  int i = blockIdx.x*256 + threadIdx.x;
  if(i < n)       row_start[i] += sums[i>>10];
  else if(i == n) row_start[n]  = E;
}

__global__ void fill_kernel(const int* __restrict__ srcv, const int* __restrict__ dstv,
                            const int* __restrict__ row_start, int* __restrict__ cnt,
                            int* __restrict__ csr, int E){
  int e = blockIdx.x*256 + threadIdx.x;
  if(e < E){
    int d = dstv[e];
    int p = atomicAdd(&cnt[d], 1);
    csr[row_start[d] + p] = srcv[e];
  }
}

// ---------------- merged prep: cvt (x->bf16) | wprep | zero ----------------
// grid = [0,6250): cvt   [6250,6330): wprep   [6330,6526): zero degcnt
__global__ __launch_bounds__(256) void prep_kernel(
    const float* __restrict__ x, unsigned short* __restrict__ xb,
    const float* __restrict__ Wrel, const float* __restrict__ Wroot,
    bf16_t* __restrict__ Bp, int4* __restrict__ zp, int zn4){
  int bid = blockIdx.x;
  if(bid < 6250){
    long i = ((long)bid*256 + threadIdx.x)*8;
    float4 q0 = *(const float4*)(x+i);
    float4 q1 = *(const float4*)(x+i+4);
    unsigned short o[8];
    o[0]=bfb(q0.x); o[1]=bfb(q0.y); o[2]=bfb(q0.z); o[3]=bfb(q0.w);
    o[4]=bfb(q1.x); o[5]=bfb(q1.y); o[6]=bfb(q1.z); o[7]=bfb(q1.w);
    *(ulong2*)(xb+i) = *(ulong2*)o;
  } else if(bid < 6330){
    int gid = (bid-6250)*256 + threadIdx.x;
    if(gid >= NLAYERS*64*64) return;
    int lane = gid & 63;
    int fg   = (gid>>6) & 63;
    int l    = gid >> 12;
    int kk = fg >> 3, cb = fg & 7;
    int kbase = kk*32 + (lane>>4)*8;
    int col   = cb*16 + (lane&15);
    bf16_t tmp[8];
    #pragma unroll
    for(int e=0;e<8;e++){
      int k = kbase + e;
      float v = (k < FDIM) ? Wrel [l*FDIM*FDIM + k*FDIM + col]
                           : Wroot[l*FDIM*FDIM + (k-FDIM)*FDIM + col];
      tmp[e] = f2bf(v);
    }
    bf16_t* o = Bp + (long)gid*8;
    #pragma unroll
    for(int e=0;e<8;e++) o[e] = tmp[e];
  } else {
    int i = (bid-6330)*256 + threadIdx.x;
    if(i < zn4) zp[i] = make_int4(0,0,0,0);
  }
}

// ---------------- per-node gather, 8 loads in flight (R8 ladder, proven best) ----
// Structural floor evidence: v3 (2-node/half-wave) +8us, v4 (predicated tail)
// +5us, fused +110us -- the kernel is random-line-throughput bound, so any
// added VALU/predication only hurts. Keep the lean ladder.
__global__ __launch_bounds__(256) void gather_kernel(const unsigned short* __restrict__ xb,
                                                     const int* __restrict__ row_start,
                                                     const int* __restrict__ csr,
                                                     unsigned short* __restrict__ agg, int n){
  int wid  = (blockIdx.x*256 + threadIdx.x) >> 6;
  int lane = threadIdx.x & 63;
  if(wid >= n) return;
  int s0 = row_start[wid];
  int s1 = row_start[wid+1];
  float ax[8] = {}, ay[8] = {};
  int i = s0;
  for(; i+8 <= s1; i += 8){
    unsigned v[8];
    #pragma unroll
    for(int j=0;j<8;j++){
      int c = csr[i+j];
      v[j] = *(const unsigned*)(xb + (size_t)c*FDIM + lane*2);
    }
    #pragma unroll
    for(int j=0;j<8;j++){ ax[j] += bfbits_lo(v[j]); ay[j] += bfbits_hi(v[j]); }
  }
  if(i+4 <= s1){
    unsigned v[4];
    #pragma unroll
    for(int j=0;j<4;j++){
      int c = csr[i+j];
      v[j] = *(const unsigned*)(xb + (size_t)c*FDIM + lane*2);
    }
    #pragma unroll
    for(int j=0;j<4;j++){ ax[j] += bfbits_lo(v[j]); ay[j] += bfbits_hi(v[j]); }
    i += 4;
  }
  if(i+2 <= s1){
    unsigned v0 = *(const unsigned*)(xb + (size_t)csr[i]*FDIM + lane*2);
    unsigned v1 = *(const unsigned*)(xb + (size_t)csr[i+1]*FDIM + lane*2);
    ax[4] += bfbits_lo(v0); ay[4] += bfbits_hi(v0);
    ax[5] += bfbits_lo(v1); ay[5] += bfbits_hi(v1);
    i += 2;
  }
  if(i < s1){
    unsigned v0 = *(const unsigned*)(xb + (size_t)csr[i]*FDIM + lane*2);
    ax[6] += bfbits_lo(v0); ay[6] += bfbits_hi(v0);
  }
  float axs = ((ax[0]+ax[1])+(ax[2]+ax[3])) + ((ax[4]+ax[5])+(ax[6]+ax[7]));
  float ays = ((ay[0]+ay[1])+(ay[2]+ay[3])) + ((ay[4]+ay[5])+(ay[6]+ay[7]));
  unsigned o = (unsigned)bfb(axs) | ((unsigned)bfb(ays) << 16);
  *(unsigned*)(agg + (size_t)wid*FDIM + lane*2) = o;
}

// ---------------- GEMM v2 (R11, proven): block-tile, A in LDS, 2 cb/wave ----
__global__ __launch_bounds__(256) void gemm_kernel(
    const bf16_t* __restrict__ Aagg, const bf16_t* __restrict__ Ain,
    const bf16_t* __restrict__ Bp, const float* __restrict__ bias,
    bf16_t* __restrict__ outB, float* __restrict__ outF,
    int relu, int resf){
  __shared__ char As[8192];          // [0,4096): agg tile, [4096,8192): xin tile
  int tid  = threadIdx.x;
  int lane = tid & 63;
  int wv   = tid >> 6;               // 0..3
  long tile0 = (long)blockIdx.x*16;

  // stage: thread t -> row t>>4, 16B chunk t&15 (coalesced global reads)
  {
    int row = tid >> 4, c16 = tid & 15;
    int so  = c16*16;
    int sw  = so ^ ((row & 7) << 4);
    ulong2 va = *(const ulong2*)((const char*)Aagg + (tile0+row)*256 + so);
    ulong2 vi = *(const ulong2*)((const char*)Ain  + (tile0+row)*256 + so);
    *(ulong2*)(As + row*256 + sw)        = va;
    *(ulong2*)(As + 4096 + row*256 + sw) = vi;
  }
  __syncthreads();

  // MFMA: this wave owns cb blocks {2wv, 2wv+1}
  int r_lo = lane & 15;
  int kgrp = lane >> 4;
  int cb0 = wv*2, cb1 = wv*2+1;
  f32x4 acc0 = {}, acc1 = {};
  #pragma unroll
  for(int kk=0;kk<8;kk++){
    const char* base = (kk<4) ? As : (As + 4096);
    int X = (kk&3)*64 + kgrp*16;
    bf16x8 a = *(const bf16x8*)(base + r_lo*256 + (X ^ ((r_lo&7)<<4)));
    bf16x8 w0 = *(const bf16x8*)(Bp + (((kk<<3)|cb0)*64 + lane)*8);
    bf16x8 w1 = *(const bf16x8*)(Bp + (((kk<<3)|cb1)*64 + lane)*8);
    acc0 = __builtin_amdgcn_mfma_f32_16x16x32_bf16(w0, a, acc0, 0, 0, 0);
    acc1 = __builtin_amdgcn_mfma_f32_16x16x32_bf16(w1, a, acc1, 0, 0, 0);
  }

  // epilogue: lane owns row tile0+r_lo, cols cb*16 + kgrp*4 .. +3
  long nrow = tile0 + r_lo;
  #pragma unroll
  for(int h=0; h<2; h++){
    int cb = h ? cb1 : cb0;
    f32x4 acc = h ? acc1 : acc0;
    int col = cb*16 + kgrp*4;
    float4 bv = *(const float4*)(bias + col);
    float v0 = acc[0] + bv.x;
    float v1 = acc[1] + bv.y;
    float v2 = acc[2] + bv.z;
    float v3 = acc[3] + bv.w;
    if(relu){ v0=fmaxf(v0,0.f); v1=fmaxf(v1,0.f); v2=fmaxf(v2,0.f); v3=fmaxf(v3,0.f); }
    if(resf){
      ushort4 rv = *(const ushort4*)(As + 4096 + r_lo*256 + ((col*2) ^ ((r_lo&7)<<4)));
      v0 += us2f(rv.x); v1 += us2f(rv.y); v2 += us2f(rv.z); v3 += us2f(rv.w);
    }
    if(outF){
      float4 o; o.x=v0; o.y=v1; o.z=v2; o.w=v3;
      *(float4*)(outF + nrow*FDIM + col) = o;
    } else {
      uint2 o;
      o.x = (unsigned)bfb(v0) | ((unsigned)bfb(v1) << 16);
      o.y = (unsigned)bfb(v2) | ((unsigned)bfb(v3) << 16);
      *(uint2*)((unsigned short*)outB + nrow*FDIM + col) = o;
    }
  }
}

extern "C" void kernel_launch(void* const* d_in, const int* in_sizes, int n_in,
                              void* d_out, int out_size, void* d_ws, size_t ws_size,
                              hipStream_t stream){
  const float* x     = (const float*)d_in[0];
  const int*   ei    = (const int*)  d_in[1];
  const float* Wrel  = (const float*)d_in[2];
  const float* brel  = (const float*)d_in[3];
  const float* Wroot = (const float*)d_in[4];
  float* out = (float*)d_out;

  const int N = NNODES;
  const int E = in_sizes[1] / 2;
  const int* srcv = ei;
  const int* dstv = ei + E;

  char* w = (char*)d_ws;
  auto alloc = [&](size_t b)->char*{ char* p = w; w += (b + 255) & ~(size_t)255; return p; };
  unsigned short* xb  = (unsigned short*)alloc((size_t)N*FDIM*2);
  unsigned short* h_a = (unsigned short*)alloc((size_t)N*FDIM*2);
  unsigned short* h_b = (unsigned short*)alloc((size_t)N*FDIM*2);
  unsigned short* agg = (unsigned short*)alloc((size_t)N*FDIM*2);
  int*    degcnt    = (int*)   alloc((size_t)2*N*4);   // [0,N): deg, [N,2N): cnt
  int*    row_start = (int*)   alloc((size_t)(N+1)*4);
  int*    csr       = (int*)   alloc((size_t)E*4);
  bf16_t* Bp        = (bf16_t*)alloc((size_t)NLAYERS*4096*8*2);
  int*    sums      = (int*)   alloc(512);
  int* deg = degcnt;
  int* cnt = degcnt + N;

  int eb = (E + 255) / 256;
  int nchunks = (N + 1023) / 1024;
  prep_kernel <<<6526, 256, 0, stream>>>(x, xb, Wrel, Wroot, Bp,
                                         (int4*)degcnt, 2*N/4);
  deg_kernel <<<eb, 256, 0, stream>>>(dstv, deg, E);
  scan1_kernel<<<nchunks, 256, 0, stream>>>(deg, row_start, sums, N);
  scan2_kernel<<<1, 128, 0, stream>>>(sums, nchunks);
  scan3_kernel<<<(N + 1 + 255)/256, 256, 0, stream>>>(row_start, sums, N, E);
  fill_kernel<<<eb, 256, 0, stream>>>(srcv, dstv, row_start, cnt, csr, E);

  const int gtiles  = N / 16;                 // 6250 blocks for gemm

  typedef unsigned short us;
  struct Lay { const us* in; us* o; int relu; int res; };
  Lay L[5] = {
    { xb,  h_a, 1, 0 },
    { h_a, h_b, 1, 1 },
    { h_b, h_a, 1, 1 },
    { h_a, h_b, 1, 1 },
    { h_b, 0,   0, 1 },
  };
  for(int l=0; l<NLAYERS; l++){
    gather_kernel<<<N/4, 256, 0, stream>>>(L[l].in, row_start, csr, agg, N);
    gemm_kernel  <<<gtiles, 256, 0, stream>>>((const bf16_t*)agg, (const bf16_t*)L[l].in,
                                              Bp + (size_t)l*4096*8,
                                              brel + l*FDIM,
                                              (bf16_t*)L[l].o, (l==4)? out : nullptr,
                                              L[l].relu, L[l].res);
  }
}